// Round 1
// baseline (339.939 us; speedup 1.0000x reference)
//
#include <hip/hip_runtime.h>
#include <hip/hip_bf16.h>

// Problem constants (fixed by setup_inputs)
#define NB   8      // batch
#define DK   256    // dk (4 mixtures x 64)
#define LL   2048   // Lq == Lk
#define DV   256    // dv
#define NMIX 4

typedef __attribute__((ext_vector_type(8))) short bf16x8;
typedef __attribute__((ext_vector_type(4))) float f32x4;

__device__ __forceinline__ unsigned short f2bf(float x) {
    unsigned int u = __float_as_uint(x);
    unsigned int r = (u + 0x7FFFu + ((u >> 16) & 1u)) >> 16;  // RNE
    return (unsigned short)r;
}
__device__ __forceinline__ float bf2f(unsigned short u) {
    return __uint_as_float(((unsigned int)u) << 16);
}

// ---------------------------------------------------------------------------
// (B, DK, LL) f32  ->  (B, LL, DK) bf16-bits   (used for both Q and K)
__global__ void transpose_cast_k(const float* __restrict__ in,
                                 unsigned short* __restrict__ out) {
    const int b  = blockIdx.z;
    const int ct = blockIdx.y;   // DK/32
    const int lt = blockIdx.x;   // LL/32
    __shared__ float tile[32][33];
    const int tx = threadIdx.x & 31;
    const int ty = threadIdx.x >> 5;   // 0..7
    const float* src = in + ((size_t)b * DK + ct * 32) * LL + lt * 32;
    #pragma unroll
    for (int r = 0; r < 4; ++r)
        tile[ty * 4 + r][tx] = src[(size_t)(ty * 4 + r) * LL + tx];
    __syncthreads();
    unsigned short* dst = out + ((size_t)b * LL + lt * 32) * DK + ct * 32;
    #pragma unroll
    for (int r = 0; r < 4; ++r)
        dst[(size_t)(ty * 4 + r) * DK + tx] = f2bf(tile[tx][ty * 4 + r]);
}

// elementwise cast (B*DV*LL) f32 -> bf16 bits (V keeps (dv, Lk) layout)
__global__ void cast_bf16_k(const float* __restrict__ in,
                            unsigned short* __restrict__ out) {
    size_t i = ((size_t)blockIdx.x * 256 + threadIdx.x) * 4;
    float4 v = *reinterpret_cast<const float4*>(in + i);
    ushort4 o;
    o.x = f2bf(v.x); o.y = f2bf(v.y); o.z = f2bf(v.z); o.w = f2bf(v.w);
    *reinterpret_cast<ushort4*>(out + i) = o;
}

// avg_query: one block per (b*DK + d) row, mean over LL
__global__ void avg_k(const float* __restrict__ q, float* __restrict__ avg) {
    const int row = blockIdx.x;
    const float* p = q + (size_t)row * LL;
    float s = 0.f;
    for (int i = threadIdx.x; i < LL; i += 256) s += p[i];
    #pragma unroll
    for (int off = 32; off >= 1; off >>= 1) s += __shfl_down(s, off);
    __shared__ float ps[4];
    if ((threadIdx.x & 63) == 0) ps[threadIdx.x >> 6] = s;
    __syncthreads();
    if (threadIdx.x == 0)
        avg[row] = (ps[0] + ps[1] + ps[2] + ps[3]) * (1.0f / LL);
}

// pi = softmax_m( w[m,:] . avg[b,:] ) ; one wave per b
__global__ void pi_k(const float* __restrict__ wgt, const float* __restrict__ avg,
                     float* __restrict__ piOut) {
    const int b = blockIdx.x;
    const int l = threadIdx.x;   // 0..63
    float part[NMIX] = {0.f, 0.f, 0.f, 0.f};
    for (int d = l; d < DK; d += 64) {
        float a = avg[b * DK + d];
        #pragma unroll
        for (int m = 0; m < NMIX; ++m) part[m] += wgt[m * DK + d] * a;
    }
    #pragma unroll
    for (int off = 1; off < 64; off <<= 1) {
        #pragma unroll
        for (int m = 0; m < NMIX; ++m) part[m] += __shfl_xor(part[m], off);
    }
    float mx = fmaxf(fmaxf(part[0], part[1]), fmaxf(part[2], part[3]));
    float e0 = __expf(part[0] - mx), e1 = __expf(part[1] - mx);
    float e2 = __expf(part[2] - mx), e3 = __expf(part[3] - mx);
    float z = e0 + e1 + e2 + e3;
    float mine = (l == 0) ? e0 : (l == 1) ? e1 : (l == 2) ? e2 : e3;
    if (l < NMIX) piOut[b * NMIX + l] = mine / z;
}

// ---------------------------------------------------------------------------
// Main fused kernel: per (b, 32-row q-tile). Two k-sweeps:
//   sweep 1: Z[m,row] = sum_k exp(S/16)   (scores bounded, no max needed)
//   sweep 2: recompute S, A = sum_m (pi_m/Z_m) exp(S/16); write attn; O += A V^T
// Wave w owns S-block (q16 = w>>1, k16 = w&1); PV: wave w owns v-range w*64..
__launch_bounds__(256, 2)
__global__ void mos_attn(const unsigned short* __restrict__ Qt,
                         const unsigned short* __restrict__ Kt,
                         const unsigned short* __restrict__ Vb,
                         const float* __restrict__ piAll,
                         float* __restrict__ out,
                         float* __restrict__ attn) {
    const int bid  = blockIdx.x;
    const int b    = bid >> 6;          // LL/32 = 64 q-tiles per batch
    const int qt   = bid & 63;
    const int tid  = threadIdx.x;
    const int w    = tid >> 6;
    const int lane = tid & 63;
    const int lg   = lane >> 4;         // 0..3
    const int lc   = lane & 15;
    const int q16  = w >> 1;
    const int k16  = w & 1;

    __shared__ __align__(16) unsigned short A_lds[32][40];  // padded: 2-way-free banks
    __shared__ float Zpart[4][NMIX][16];
    __shared__ float pish[NMIX];

    if (tid < NMIX) pish[tid] = piAll[b * NMIX + tid];

    // Hoist Q fragments: A[q, c] = Qt[b][q][c]; per-lane 16B contiguous
    const int qbase = qt * 32 + q16 * 16;
    bf16x8 qf[NMIX][2];
    {
        const unsigned short* qrow = Qt + ((size_t)b * LL + qbase + lc) * DK;
        #pragma unroll
        for (int m = 0; m < NMIX; ++m)
            #pragma unroll
            for (int ch = 0; ch < 2; ++ch)
                qf[m][ch] = *reinterpret_cast<const bf16x8*>(qrow + m * 64 + ch * 32 + lg * 8);
    }

    const unsigned short* kb0 = Kt + (size_t)b * LL * DK;
    const float invT = 1.0f / 16.0f;

    // ---- sweep 1: denominators ----
    float zsum[NMIX][4];
    #pragma unroll
    for (int m = 0; m < NMIX; ++m)
        #pragma unroll
        for (int r = 0; r < 4; ++r) zsum[m][r] = 0.f;

    for (int kt2 = 0; kt2 < 64; ++kt2) {
        const unsigned short* krow = kb0 + ((size_t)(kt2 * 32 + k16 * 16 + lc)) * DK;
        #pragma unroll
        for (int m = 0; m < NMIX; ++m) {
            f32x4 s = {0.f, 0.f, 0.f, 0.f};
            bf16x8 kf0 = *reinterpret_cast<const bf16x8*>(krow + m * 64 + lg * 8);
            bf16x8 kf1 = *reinterpret_cast<const bf16x8*>(krow + m * 64 + 32 + lg * 8);
            s = __builtin_amdgcn_mfma_f32_16x16x32_bf16(qf[m][0], kf0, s, 0, 0, 0);
            s = __builtin_amdgcn_mfma_f32_16x16x32_bf16(qf[m][1], kf1, s, 0, 0, 0);
            #pragma unroll
            for (int r = 0; r < 4; ++r) zsum[m][r] += __expf(s[r] * invT);
        }
    }
    // reduce over the 16 lanes (cols) of each group
    #pragma unroll
    for (int m = 0; m < NMIX; ++m)
        #pragma unroll
        for (int r = 0; r < 4; ++r) {
            float v = zsum[m][r];
            v += __shfl_xor(v, 1);
            v += __shfl_xor(v, 2);
            v += __shfl_xor(v, 4);
            v += __shfl_xor(v, 8);
            zsum[m][r] = v;
        }
    if (lc == 0) {
        #pragma unroll
        for (int m = 0; m < NMIX; ++m)
            #pragma unroll
            for (int r = 0; r < 4; ++r) Zpart[w][m][lg * 4 + r] = zsum[m][r];
    }
    __syncthreads();

    float scl[NMIX][4];
    #pragma unroll
    for (int m = 0; m < NMIX; ++m)
        #pragma unroll
        for (int r = 0; r < 4; ++r) {
            float z = Zpart[q16 * 2][m][lg * 4 + r] + Zpart[q16 * 2 + 1][m][lg * 4 + r];
            scl[m][r] = pish[m] / z;
        }

    // ---- sweep 2: emit attn + accumulate O ----
    f32x4 oacc[2][4];
    #pragma unroll
    for (int qq = 0; qq < 2; ++qq)
        #pragma unroll
        for (int j = 0; j < 4; ++j) oacc[qq][j] = (f32x4){0.f, 0.f, 0.f, 0.f};

    const unsigned short* vbp = Vb + (size_t)b * DV * LL;
    float* attnB = attn + ((size_t)b * LL + qt * 32) * LL;

    for (int kt2 = 0; kt2 < 64; ++kt2) {
        const unsigned short* krow = kb0 + ((size_t)(kt2 * 32 + k16 * 16 + lc)) * DK;
        float av[4] = {0.f, 0.f, 0.f, 0.f};
        #pragma unroll
        for (int m = 0; m < NMIX; ++m) {
            f32x4 s = {0.f, 0.f, 0.f, 0.f};
            bf16x8 kf0 = *reinterpret_cast<const bf16x8*>(krow + m * 64 + lg * 8);
            bf16x8 kf1 = *reinterpret_cast<const bf16x8*>(krow + m * 64 + 32 + lg * 8);
            s = __builtin_amdgcn_mfma_f32_16x16x32_bf16(qf[m][0], kf0, s, 0, 0, 0);
            s = __builtin_amdgcn_mfma_f32_16x16x32_bf16(qf[m][1], kf1, s, 0, 0, 0);
            #pragma unroll
            for (int r = 0; r < 4; ++r) av[r] += scl[m][r] * __expf(s[r] * invT);
        }
        #pragma unroll
        for (int r = 0; r < 4; ++r)
            A_lds[q16 * 16 + lg * 4 + r][k16 * 16 + lc] = f2bf(av[r]);
        __syncthreads();

        // coalesced attn write (float4 rows from LDS)
        {
            const int row = tid >> 3;
            const int c4  = (tid & 7) * 4;
            float4 vv;
            vv.x = bf2f(A_lds[row][c4 + 0]);
            vv.y = bf2f(A_lds[row][c4 + 1]);
            vv.z = bf2f(A_lds[row][c4 + 2]);
            vv.w = bf2f(A_lds[row][c4 + 3]);
            *reinterpret_cast<float4*>(attnB + (size_t)row * LL + kt2 * 32 + c4) = vv;
        }

        // PV: O[q, v] += A[q, kk] * V^T[kk, v]
        bf16x8 af[2];
        #pragma unroll
        for (int qq = 0; qq < 2; ++qq)
            af[qq] = *reinterpret_cast<const bf16x8*>(&A_lds[qq * 16 + lc][lg * 8]);
        #pragma unroll
        for (int j = 0; j < 4; ++j) {
            bf16x8 vf = *reinterpret_cast<const bf16x8*>(
                vbp + ((size_t)(w * 64 + j * 16 + lc)) * LL + kt2 * 32 + lg * 8);
            #pragma unroll
            for (int qq = 0; qq < 2; ++qq)
                oacc[qq][j] = __builtin_amdgcn_mfma_f32_16x16x32_bf16(af[qq], vf, oacc[qq][j], 0, 0, 0);
        }
        __syncthreads();   // A_lds reused next iteration
    }

    // write O: rows qt*32 + qq*16 + lg*4 + r ; cols w*64 + j*16 + lc
    #pragma unroll
    for (int qq = 0; qq < 2; ++qq)
        #pragma unroll
        for (int j = 0; j < 4; ++j)
            #pragma unroll
            for (int r = 0; r < 4; ++r) {
                size_t q = (size_t)b * LL + qt * 32 + qq * 16 + lg * 4 + r;
                out[q * DV + w * 64 + j * 16 + lc] = oacc[qq][j][r];
            }
}

// ---------------------------------------------------------------------------
extern "C" void kernel_launch(void* const* d_in, const int* in_sizes, int n_in,
                              void* d_out, int out_size, void* d_ws, size_t ws_size,
                              hipStream_t stream) {
    const float* query   = (const float*)d_in[0];   // (8, 256, 2048)
    const float* key     = (const float*)d_in[1];   // (8, 256, 2048)
    const float* value   = (const float*)d_in[2];   // (8, 256, 2048)
    const float* weights = (const float*)d_in[3];   // (4, 256)

    float* out  = (float*)d_out;                         // (8, 2048, 256)
    float* attn = out + (size_t)NB * LL * DV;            // (8, 2048, 2048)

    // workspace layout (needs ~25.2 MB)
    char* ws = (char*)d_ws;
    float* avg = (float*)ws;                             // 8*256 f32
    float* pi  = (float*)(ws + 8192);                    // 8*4 f32
    unsigned short* Qt = (unsigned short*)(ws + 16384);  // (8,2048,256) bf16
    unsigned short* Kt = Qt + (size_t)NB * LL * DK;
    unsigned short* Vb = Kt + (size_t)NB * LL * DK;      // (8,256,2048) bf16

    transpose_cast_k<<<dim3(LL / 32, DK / 32, NB), 256, 0, stream>>>(query, Qt);
    transpose_cast_k<<<dim3(LL / 32, DK / 32, NB), 256, 0, stream>>>(key, Kt);
    cast_bf16_k<<<(NB * DV * LL) / 1024, 256, 0, stream>>>(value, Vb);
    avg_k<<<NB * DK, 256, 0, stream>>>(query, avg);
    pi_k<<<NB, 64, 0, stream>>>(weights, avg, pi);
    mos_attn<<<NB * (LL / 32), 256, 0, stream>>>(Qt, Kt, Vb, pi, out, attn);
}